// Round 4
// baseline (5224.560 us; speedup 1.0000x reference)
//
#include <hip/hip_runtime.h>
#include <hip/hip_fp16.h>

// ============================================================================
// SpectralProcessingModel on MI355X (gfx950)
//
// Pipeline:
//   fft_feat: rfft2(64x64, ortho) + fftshift(h) + row reorder -> feat (2,2112,32)
//   init_shift: feat @ init_w.T + init_b, shifted right by 1, slot 0 = cond*dc_w+dc_b
//   8 x transformer layer:
//     ln1 -> qkv GEMM (f16 out) -> rope(add)+head split (+V transpose) ->
//     S = QK^T (causal-tile-skipped, scaled) -> softmax(in-place, causal) ->
//     O = P V (causal K-limited) -> proj GEMM (+residual) -> ln2 ->
//     ff1(+exact gelu) -> ff2(+residual)
//   heads: (W @ t4^T) with transposed epilogue writing (b,ci,code,p)
//
// All heavy GEMMs: f16 inputs, fp32 MFMA accum, 128x128 tile, 4 waves,
// BK=32, global_load_lds 16B staging (m97 structure).  ~315 MB workspace.
// ============================================================================

typedef _Float16 f16;
typedef _Float16 f16x2 __attribute__((ext_vector_type(2)));
typedef _Float16 f16x4 __attribute__((ext_vector_type(4)));
typedef _Float16 f16x8 __attribute__((ext_vector_type(8)));
typedef float f32x4 __attribute__((ext_vector_type(4)));

#define DEV __device__ __forceinline__

DEV void load_lds16(const f16* g, f16* l) {
  // dest must be wave-uniform base + lane*16B; our per-lane ptr equals exactly that.
  __builtin_amdgcn_global_load_lds((const __attribute__((address_space(1))) void*)(g),
                                   (__attribute__((address_space(3))) void*)(l), 16, 0, 0);
}

// ---------------------------------------------------------------------------
// FFT + reorder + feature pack.  One block per (b,c) image.
// feat[b][p][c] = Re, feat[b][p][16+c] = Im of shifted/reordered rfft2.
// ---------------------------------------------------------------------------
__global__ __launch_bounds__(256) void fft_feat_kernel(const float* __restrict__ x,
                                                       float* __restrict__ feat) {
  const int img = blockIdx.x;            // 0..31
  const int b = img >> 4, c = img & 15;
  __shared__ float xs[64 * 64];
  __shared__ float wre[64 * 33];
  __shared__ float wim[64 * 33];
  __shared__ float ct[64];
  __shared__ float st[64];
  const int tid = threadIdx.x;
  if (tid < 64) {
    float th = 0.09817477042468103f * (float)tid;  // 2*pi/64
    ct[tid] = cosf(th);
    st[tid] = sinf(th);
  }
  const float* xp = x + (size_t)img * 4096;
  for (int i = tid; i < 4096; i += 256) xs[i] = xp[i];
  __syncthreads();
  // pass A: real FFT along width. W[y][kx], e^{-i 2pi kx x/64}
  for (int i = tid; i < 64 * 33; i += 256) {
    int y = i / 33, kx = i - y * 33;
    float re = 0.f, im = 0.f;
    for (int xx = 0; xx < 64; ++xx) {
      float v = xs[y * 64 + xx];
      int idx = (kx * xx) & 63;
      re += v * ct[idx];
      im -= v * st[idx];
    }
    wre[i] = re;
    wim[i] = im;
  }
  __syncthreads();
  // pass B: FFT along height, fftshift + row reorder folded into ky choice.
  for (int i = tid; i < 64 * 33; i += 256) {
    int r = i / 33, kx = i - r * 33;
    int row;                       // source row in the SHIFTED array
    if (r == 0)      row = 32;
    else if (r == 63) row = 0;
    else if (r & 1)  row = 32 + (r + 1) / 2;
    else             row = 32 - r / 2;
    int ky = (row + 32) & 63;      // undo fftshift
    float re = 0.f, im = 0.f;
    for (int y = 0; y < 64; ++y) {
      int idx = (ky * y) & 63;
      float cr = ct[idx], sr = st[idx];
      float ar = wre[y * 33 + kx], ai = wim[y * 33 + kx];
      re += ar * cr + ai * sr;
      im += ai * cr - ar * sr;
    }
    re *= (1.0f / 64.0f);   // ortho norm 1/sqrt(4096)
    im *= (1.0f / 64.0f);
    float* fb = feat + ((size_t)b * 2112 + i) * 32;
    fb[c] = re;
    fb[16 + c] = im;
  }
}

// ---------------------------------------------------------------------------
// t[b][p][d]: p==0 -> cond[b]*dc_w[d]+dc_b[d]; else feat[b][p-1] @ init_w[d]
// ---------------------------------------------------------------------------
__global__ __launch_bounds__(256) void init_shift_kernel(
    const float* __restrict__ feat, const float* __restrict__ iw,
    const float* __restrict__ ib, const float* __restrict__ cond,
    const float* __restrict__ dcw, const float* __restrict__ dcb,
    float* __restrict__ t) {
  const int idx = blockIdx.x * 256 + threadIdx.x;   // over 2*2112*1024
  if (idx >= 2 * 2112 * 1024) return;
  const int d = idx & 1023;
  const int bp = idx >> 10;
  const int b = bp / 2112, p = bp - b * 2112;
  float v;
  if (p == 0) {
    v = cond[b] * dcw[d] + dcb[d];
  } else {
    const float4* f4 = (const float4*)(feat + ((size_t)b * 2112 + (p - 1)) * 32);
    const float4* w4 = (const float4*)(iw + (size_t)d * 32);
    float acc = ib[d];
#pragma unroll
    for (int k = 0; k < 8; ++k) {
      const float4 a = f4[k], w = w4[k];
      acc += a.x * w.x + a.y * w.y + a.z * w.z + a.w * w.w;
    }
    v = acc;
  }
  t[idx] = v;
}

// ---------------------------------------------------------------------------
__global__ __launch_bounds__(256) void f32_to_f16_kernel(const float* __restrict__ in,
                                                         f16* __restrict__ out,
                                                         const int n4) {
  int i = blockIdx.x * 256 + threadIdx.x;
  const int stride = gridDim.x * 256;
  for (; i < n4; i += stride) {
    const float4 v = ((const float4*)in)[i];
    f16x4 o;
    o[0] = (f16)v.x; o[1] = (f16)v.y; o[2] = (f16)v.z; o[3] = (f16)v.w;
    ((f16x4*)out)[i] = o;
  }
}

// Fused 4-segment f32->f16 convert (one launch per layer's weights).
__global__ __launch_bounds__(256) void convert4_kernel(
    const float* __restrict__ s0, f16* __restrict__ d0, const int n0,
    const float* __restrict__ s1, f16* __restrict__ d1, const int n1,
    const float* __restrict__ s2, f16* __restrict__ d2, const int n2,
    const float* __restrict__ s3, f16* __restrict__ d3, const int n3) {
  int i = blockIdx.x * 256 + threadIdx.x;   // in float4 units
  const int total = n0 + n1 + n2 + n3;
  const int stride = gridDim.x * 256;
  for (; i < total; i += stride) {
    const float* s; f16* d; int j = i;
    if (j < n0)            { s = s0; d = d0; }
    else { j -= n0; if (j < n1) { s = s1; d = d1; }
    else { j -= n1; if (j < n2) { s = s2; d = d2; }
    else { j -= n2;          s = s3; d = d3; } } }
    const float4 v = ((const float4*)s)[j];
    f16x4 o;
    o[0] = (f16)v.x; o[1] = (f16)v.y; o[2] = (f16)v.z; o[3] = (f16)v.w;
    ((f16x4*)d)[j] = o;
  }
}

// ---------------------------------------------------------------------------
// LayerNorm (biased var, eps 1e-5), fp32 in -> f16 out. One block per row.
// ---------------------------------------------------------------------------
__global__ __launch_bounds__(256) void ln_kernel(const float* __restrict__ tin,
                                                 const float* __restrict__ g,
                                                 const float* __restrict__ bb,
                                                 f16* __restrict__ outp) {
  const int row = blockIdx.x;
  const int tid = threadIdx.x, lane = tid & 63, wid = tid >> 6;
  const float4 v = ((const float4*)(tin + (size_t)row * 1024))[tid];
  float s = v.x + v.y + v.z + v.w;
  float s2 = v.x * v.x + v.y * v.y + v.z * v.z + v.w * v.w;
#pragma unroll
  for (int o = 32; o; o >>= 1) {
    s += __shfl_down(s, o);
    s2 += __shfl_down(s2, o);
  }
  __shared__ float red[8];
  if (lane == 0) { red[wid] = s; red[4 + wid] = s2; }
  __syncthreads();
  const float mean = (red[0] + red[1] + red[2] + red[3]) * (1.f / 1024.f);
  const float var = (red[4] + red[5] + red[6] + red[7]) * (1.f / 1024.f) - mean * mean;
  const float rstd = rsqrtf(var + 1e-5f);
  const float4 gv = ((const float4*)g)[tid];
  const float4 bv = ((const float4*)bb)[tid];
  f16x4 o;
  o[0] = (f16)((v.x - mean) * rstd * gv.x + bv.x);
  o[1] = (f16)((v.y - mean) * rstd * gv.y + bv.y);
  o[2] = (f16)((v.z - mean) * rstd * gv.z + bv.z);
  o[3] = (f16)((v.w - mean) * rstd * gv.w + bv.w);
  ((f16x4*)(outp + (size_t)row * 1024))[tid] = o;
}

// ---------------------------------------------------------------------------
// RoPE (x + rope(x)) for q,k + head split to [bh][p][d]; V -> [bh][d][p] f16.
// Reads f16 qkv; f16x2-vectorized (one thread per dh-pair).
// grid: (33 p-tiles, 16 bh), 256 threads.
// ---------------------------------------------------------------------------
__global__ __launch_bounds__(256) void rope_split_kernel(const f16* __restrict__ qkv,
                                                         f16* __restrict__ qr,
                                                         f16* __restrict__ kr,
                                                         f16* __restrict__ vt) {
  const int z = blockIdx.y;   // b*8+h
  const int pt = blockIdx.x;  // 0..32
  const int b = z >> 3, h = z & 7;
  const int p0 = pt * 64;
  const int tid = threadIdx.x;
  __shared__ f16 vtile[64][130];

  for (int it = 0; it < 8; ++it) {
    int idx = it * 256 + tid;       // 64 rows x 32 dh-pairs
    int pr = idx >> 5, dp = idx & 31;
    int dh = dp * 2;
    int p = p0 + pr;
    const size_t base = ((size_t)(b * 2112 + p)) * 3072 + h * 128;
    float sn0, cs0, sn1, cs1;
    {
      float div0 = expf((float)dh * -0.14391156831212787f);        // -ln(1e4)/64
      float div1 = expf((float)(dh + 1) * -0.14391156831212787f);
      sincosf((float)p * div0, &sn0, &cs0);
      sincosf((float)p * div1, &sn1, &cs1);
    }
    // q (out = x + rope(x)); pairs (dh, dh+64)
    {
      const f16x2 a = *(const f16x2*)(qkv + base + dh);
      const f16x2 c = *(const f16x2*)(qkv + base + 64 + dh);
      f16x2 lo, hi;
      lo[0] = (f16)((float)a[0] + (float)a[0] * cs0 - (float)c[0] * sn0);
      lo[1] = (f16)((float)a[1] + (float)a[1] * cs1 - (float)c[1] * sn1);
      hi[0] = (f16)((float)c[0] + (float)c[0] * cs0 + (float)a[0] * sn0);
      hi[1] = (f16)((float)c[1] + (float)c[1] * cs1 + (float)a[1] * sn1);
      f16* qo = qr + ((size_t)z * 2112 + p) * 128;
      *(f16x2*)(qo + dh) = lo;
      *(f16x2*)(qo + 64 + dh) = hi;
    }
    // k
    {
      const f16x2 a = *(const f16x2*)(qkv + base + 1024 + dh);
      const f16x2 c = *(const f16x2*)(qkv + base + 1024 + 64 + dh);
      f16x2 lo, hi;
      lo[0] = (f16)((float)a[0] + (float)a[0] * cs0 - (float)c[0] * sn0);
      lo[1] = (f16)((float)a[1] + (float)a[1] * cs1 - (float)c[1] * sn1);
      hi[0] = (f16)((float)c[0] + (float)c[0] * cs0 + (float)a[0] * sn0);
      hi[1] = (f16)((float)c[1] + (float)c[1] * cs1 + (float)a[1] * sn1);
      f16* ko = kr + ((size_t)z * 2112 + p) * 128;
      *(f16x2*)(ko + dh) = lo;
      *(f16x2*)(ko + 64 + dh) = hi;
    }
    // v stage (no rope)
    {
      *(f16x2*)(&vtile[pr][dh]) = *(const f16x2*)(qkv + base + 2048 + dh);
      *(f16x2*)(&vtile[pr][64 + dh]) = *(const f16x2*)(qkv + base + 2048 + 64 + dh);
    }
  }
  __syncthreads();
  for (int it = 0; it < 16; ++it) {
    int idx = it * 256 + tid;       // 128 d x 32 pc-pairs
    int d = idx >> 5, pcp = idx & 31;
    int pc = pcp * 2;
    f16x2 o;
    o[0] = vtile[pc][d];
    o[1] = vtile[pc + 1][d];
    *(f16x2*)(vt + ((size_t)z * 128 + d) * 2112 + p0 + pc) = o;
  }
}

// ---------------------------------------------------------------------------
// In-place causal softmax on S[z][q][*] (f16). One block per row.
// f16x8-vectorized global I/O; zero-fills only up to the q-tile bound
// (PV's K-loop stops there too).
// ---------------------------------------------------------------------------
__global__ __launch_bounds__(256) void softmax_kernel(f16* S) {
  const int z = blockIdx.y, q = blockIdx.x;
  f16* row = S + ((size_t)z * 2112 + q) * 2112;
  const int valid = q + 1;
  const int fill0 = ((q >> 7) + 1) << 7;
  const int fill = fill0 < 2112 ? fill0 : 2112;   // multiple of 128
  const int nchunk = fill >> 3;                   // f16x8 chunks to write
  __shared__ float buf[2112];
  __shared__ float red[4];
  const int tid = threadIdx.x, lane = tid & 63, wid = tid >> 6;
  float m = -1e30f;
  // Load (vector): chunks straddling `valid` are still fully inside the
  // written diagonal tile, so the 16B load is safe.
  for (int c = tid; c * 8 < valid; c += 256) {
    const f16x8 v8 = *(const f16x8*)(row + c * 8);
#pragma unroll
    for (int e = 0; e < 8; ++e) {
      const int i = c * 8 + e;
      const float v = (float)v8[e];
      if (i < valid) { buf[i] = v; m = fmaxf(m, v); }
    }
  }
#pragma unroll
  for (int o = 32; o; o >>= 1) m = fmaxf(m, __shfl_down(m, o));
  if (lane == 0) red[wid] = m;
  __syncthreads();
  m = fmaxf(fmaxf(red[0], red[1]), fmaxf(red[2], red[3]));
  __syncthreads();
  float s = 0.f;
  for (int i = tid; i < valid; i += 256) {
    const float e = expf(buf[i] - m);
    buf[i] = e;
    s += e;
  }
#pragma unroll
  for (int o = 32; o; o >>= 1) s += __shfl_down(s, o);
  if (lane == 0) red[wid] = s;
  __syncthreads();
  const float inv = 1.f / (red[0] + red[1] + red[2] + red[3]);
  for (int c = tid; c < nchunk; c += 256) {
    f16x8 o;
#pragma unroll
    for (int e = 0; e < 8; ++e) {
      const int i = c * 8 + e;
      o[e] = (i < valid) ? (f16)(buf[i] * inv) : (f16)0.f;
    }
    *(f16x8*)(row + c * 8) = o;
  }
}

// ---------------------------------------------------------------------------
// Generic f16 MFMA GEMM: C[m][n] = sum_k A[m][k] * B[n][k]  (both row-major,
// K contiguous).  128x128 tile, 4 waves (2x2), BK=32, global_load_lds.
// MODE epilogues:
//   0: outF[m*ldc+n] = acc + bias[n]                       (fp32 out)
//   1: outF[m*ldc+n] = acc + bias[n] + res[m*ldc+n]        (proj/ff2, res==outF ok)
//   2: outH[m*ldc+n] = gelu_exact(acc + bias[n])           (ff1)
//   3: head: outF[((b*16+ci)*1024+code)*2112+p] = acc+bias[m]; m->(code,ci), n->(b,p)
//   4: outH[z*2112^2 + m*2112 + n] = acc * rsqrt(128)      (S; skips masked tiles)
//   5: outH[(b*2112+m)*1024 + h*128 + n] = acc  (PV; K limited to m0+128, causal)
//   6: outH[m*ldc+n] = (f16)(acc + bias[n])                (qkv, f16 out)
// ---------------------------------------------------------------------------
template <int MODE>
__global__ __launch_bounds__(256) void gemm_f16(
    const f16* __restrict__ A, const f16* __restrict__ B,
    const int M, const int N, const int K, const int lda, const int ldb,
    const long sA, const long sB,
    const float* __restrict__ bias,
    float* outF, f16* outH, const float* res, const int ldc) {
  const int tn = blockIdx.x, tm = blockIdx.y, z = blockIdx.z;
  const int m0 = tm * 128, n0 = tn * 128;
  if (MODE == 4 && n0 > m0 + 127) return;   // fully-masked causal tile
  const f16* Ab = A + (size_t)z * sA;
  const f16* Bb = B + (size_t)z * sB;
  __shared__ __align__(16) f16 Ash[4096];
  __shared__ __align__(16) f16 Bsh[4096];
  const int tid = threadIdx.x;
  const int wave = tid >> 6, lane = tid & 63;
  const int wr = wave >> 1, wc = wave & 1;

  f32x4 acc[4][4];
#pragma unroll
  for (int i = 0; i < 4; ++i)
#pragma unroll
    for (int j = 0; j < 4; ++j)
#pragma unroll
      for (int r = 0; r < 4; ++r) acc[i][j][r] = 0.f;

  const int srow = wave * 16 + (lane >> 2);  // staged row (+ s*64)
  const int scol = (lane & 3) * 8;           // staged k-col
  const int ldsoff = wave * 512 + lane * 8;  // f16 elems (+ s*2048)
  const int arow = lane & 15, kg = lane >> 4;

  // Causal K-limit for PV: S columns beyond m0+127 are zero / never needed.
  const int Kend = (MODE == 5) ? (K < m0 + 128 ? K : m0 + 128) : K;

  for (int k0 = 0; k0 < Kend; k0 += 32) {
#pragma unroll
    for (int s = 0; s < 2; ++s) {
      int ar = m0 + srow + s * 64; ar = ar < M ? ar : M - 1;
      load_lds16(Ab + (size_t)ar * lda + k0 + scol, Ash + s * 2048 + ldsoff);
      int br = n0 + srow + s * 64; br = br < N ? br : N - 1;
      load_lds16(Bb + (size_t)br * ldb + k0 + scol, Bsh + s * 2048 + ldsoff);
    }
    __syncthreads();
    f16x8 af[4], bf[4];
#pragma unroll
    for (int i = 0; i < 4; ++i)
      af[i] = *(const f16x8*)(Ash + (wr * 64 + i * 16 + arow) * 32 + kg * 8);
#pragma unroll
    for (int j = 0; j < 4; ++j)
      bf[j] = *(const f16x8*)(Bsh + (wc * 64 + j * 16 + arow) * 32 + kg * 8);
#pragma unroll
    for (int i = 0; i < 4; ++i)
#pragma unroll
      for (int j = 0; j < 4; ++j)
        acc[i][j] = __builtin_amdgcn_mfma_f32_16x16x32_f16(af[i], bf[j], acc[i][j], 0, 0, 0);
    __syncthreads();
  }

#pragma unroll
  for (int i = 0; i < 4; ++i) {
#pragma unroll
    for (int r = 0; r < 4; ++r) {
      const int m = m0 + wr * 64 + i * 16 + (lane >> 4) * 4 + r;
#pragma unroll
      for (int j = 0; j < 4; ++j) {
        const int n = n0 + wc * 64 + j * 16 + (lane & 15);
        float v = acc[i][j][r];
        if (MODE == 0) {
          if (m < M && n < N) outF[(size_t)m * ldc + n] = v + bias[n];
        } else if (MODE == 1) {
          if (m < M && n < N) {
            float t0 = res[(size_t)m * ldc + n];
            outF[(size_t)m * ldc + n] = v + bias[n] + t0;
          }
        } else if (MODE == 2) {
          if (m < M && n < N) {
            float g0 = v + bias[n];
            g0 = 0.5f * g0 * (1.f + erff(g0 * 0.70710678118654752f));
            outH[(size_t)m * ldc + n] = (f16)g0;
          }
        } else if (MODE == 3) {
          if (m < M && n < N) {
            int code = m >> 4, ci = m & 15;
            int bb2 = (n >= 2112) ? 1 : 0;
            int p = n - bb2 * 2112;
            outF[((size_t)(bb2 * 16 + ci) * 1024 + code) * 2112 + p] = v + bias[m];
          }
        } else if (MODE == 4) {
          if (m < M && n < N)
            outH[(size_t)z * 4460544 + (size_t)m * 2112 + n] =
                (f16)(v * 0.08838834764831845f);
        } else if (MODE == 5) {
          int bb2 = z >> 3, h = z & 7;
          if (m < M && n < N)
            outH[((size_t)(bb2 * 2112 + m)) * 1024 + h * 128 + n] = (f16)v;
        } else {  // MODE 6
          if (m < M && n < N) outH[(size_t)m * ldc + n] = (f16)(v + bias[n]);
        }
      }
    }
  }
}

// ---------------------------------------------------------------------------
extern "C" void kernel_launch(void* const* d_in, const int* in_sizes, int n_in,
                              void* d_out, int out_size, void* d_ws, size_t ws_size,
                              hipStream_t stream) {
  const float* x      = (const float*)d_in[0];
  const float* cond   = (const float*)d_in[1];
  const float* init_w = (const float*)d_in[2];
  const float* init_b = (const float*)d_in[3];
  const float* dc_w   = (const float*)d_in[4];
  const float* dc_b   = (const float*)d_in[5];
  const float* ln1_g  = (const float*)d_in[6];
  const float* ln1_b  = (const float*)d_in[7];
  const float* qkv_w  = (const float*)d_in[8];
  const float* qkv_b  = (const float*)d_in[9];
  const float* proj_w = (const float*)d_in[10];
  const float* proj_b = (const float*)d_in[11];
  const float* ln2_g  = (const float*)d_in[12];
  const float* ln2_b  = (const float*)d_in[13];
  const float* ff1_w  = (const float*)d_in[14];
  const float* ff1_b  = (const float*)d_in[15];
  const float* ff2_w  = (const float*)d_in[16];
  const float* ff2_b  = (const float*)d_in[17];
  const float* mag_w  = (const float*)d_in[18];
  const float* mag_b  = (const float*)d_in[19];
  const float* phase_w = (const float*)d_in[20];
  const float* phase_b = (const float*)d_in[21];

  char* ws = (char*)d_ws;
  size_t off = 0;
  auto alloc = [&](size_t bytes) -> void* {
    void* p = ws + off;
    off += (bytes + 255) & ~(size_t)255;
    return p;
  };
  float* feat = (float*)alloc((size_t)2 * 2112 * 32 * 4);
  float* t    = (float*)alloc((size_t)4224 * 1024 * 4);
  f16* tln    = (f16*)alloc((size_t)4224 * 1024 * 2);
  f16* qkvh   = (f16*)alloc((size_t)4224 * 3072 * 2);
  f16* qr     = (f16*)alloc((size_t)16 * 2112 * 128 * 2);
  f16* kr     = (f16*)alloc((size_t)16 * 2112 * 128 * 2);
  f16* vt     = (f16*)alloc((size_t)16 * 2112 * 128 * 2);
  f16* S      = (f16*)alloc((size_t)16 * 2112 * 2112 * 2);
  f16* ao     = (f16*)alloc((size_t)4224 * 1024 * 2);
  f16* ffh    = (f16*)alloc((size_t)4224 * 4096 * 2);
  f16* tf16   = (f16*)alloc((size_t)4224 * 1024 * 2);
  f16* wq     = (f16*)alloc((size_t)3145728 * 2);
  f16* wp     = (f16*)alloc((size_t)1048576 * 2);
  f16* w1     = (f16*)alloc((size_t)4194304 * 2);
  f16* w2     = (f16*)alloc((size_t)4194304 * 2);
  f16* wh     = (f16*)alloc((size_t)8388608 * 2);
  (void)ws_size; (void)n_in; (void)in_sizes; (void)out_size;

  fft_feat_kernel<<<32, 256, 0, stream>>>(x, feat);
  init_shift_kernel<<<16896, 256, 0, stream>>>(feat, init_w, init_b, cond, dc_w, dc_b, t);

  for (int l = 0; l < 8; ++l) {
    convert4_kernel<<<2048, 256, 0, stream>>>(
        qkv_w + (size_t)l * 3145728, wq, 3145728 / 4,
        proj_w + (size_t)l * 1048576, wp, 1048576 / 4,
        ff1_w + (size_t)l * 4194304, w1, 4194304 / 4,
        ff2_w + (size_t)l * 4194304, w2, 4194304 / 4);

    ln_kernel<<<4224, 256, 0, stream>>>(t, ln1_g + l * 1024, ln1_b + l * 1024, tln);
    gemm_f16<6><<<dim3(24, 33, 1), 256, 0, stream>>>(
        tln, wq, 4224, 3072, 1024, 1024, 1024, 0, 0,
        qkv_b + l * 3072, nullptr, qkvh, nullptr, 3072);
    rope_split_kernel<<<dim3(33, 16), 256, 0, stream>>>(qkvh, qr, kr, vt);
    gemm_f16<4><<<dim3(17, 17, 16), 256, 0, stream>>>(
        qr, kr, 2112, 2112, 128, 128, 128, (long)2112 * 128, (long)2112 * 128,
        nullptr, nullptr, S, nullptr, 0);
    softmax_kernel<<<dim3(2112, 16), 256, 0, stream>>>(S);
    gemm_f16<5><<<dim3(1, 17, 16), 256, 0, stream>>>(
        S, vt, 2112, 128, 2112, 2112, 2112, (long)2112 * 2112, (long)128 * 2112,
        nullptr, nullptr, ao, nullptr, 0);
    gemm_f16<1><<<dim3(8, 33, 1), 256, 0, stream>>>(
        ao, wp, 4224, 1024, 1024, 1024, 1024, 0, 0,
        proj_b + l * 1024, t, nullptr, t, 1024);

    ln_kernel<<<4224, 256, 0, stream>>>(t, ln2_g + l * 1024, ln2_b + l * 1024, tln);
    gemm_f16<2><<<dim3(32, 33, 1), 256, 0, stream>>>(
        tln, w1, 4224, 4096, 1024, 1024, 1024, 0, 0,
        ff1_b + l * 4096, nullptr, ffh, nullptr, 4096);
    gemm_f16<1><<<dim3(8, 33, 1), 256, 0, stream>>>(
        ffh, w2, 4224, 1024, 4096, 4096, 4096, 0, 0,
        ff2_b + l * 1024, t, nullptr, t, 1024);
  }

  f32_to_f16_kernel<<<1024, 256, 0, stream>>>(t, tf16, (4224 * 1024) / 4);

  f32_to_f16_kernel<<<2048, 256, 0, stream>>>(mag_w, wh, 8388608 / 4);
  gemm_f16<3><<<dim3(33, 128, 1), 256, 0, stream>>>(
      wh, tf16, 16384, 4224, 512, 512, 1024, 0, 0,
      mag_b, (float*)d_out, nullptr, nullptr, 0);

  f32_to_f16_kernel<<<2048, 256, 0, stream>>>(phase_w, wh, 8388608 / 4);
  gemm_f16<3><<<dim3(33, 128, 1), 256, 0, stream>>>(
      wh, tf16 + 512, 16384, 4224, 512, 512, 1024, 0, 0,
      phase_b, (float*)d_out + 69206016, nullptr, nullptr, 0);
}

// Round 5
// 4994.633 us; speedup vs baseline: 1.0460x; 1.0460x over previous
//
#include <hip/hip_runtime.h>
#include <hip/hip_fp16.h>

// ============================================================================
// SpectralProcessingModel on MI355X (gfx950)
//
// Pipeline:
//   fft_feat: rfft2(64x64, ortho) + fftshift(h) + row reorder -> feat (2,2112,32)
//   init_shift: feat @ init_w.T + init_b, shifted right by 1, slot 0 = cond*dc_w+dc_b
//   8 x transformer layer:
//     ln1 -> qkv GEMM (f16 out) -> rope(add)+head split (+V transpose) ->
//     fused flash attention (QK^T + online softmax + PV, causal) ->
//     proj GEMM (+residual) -> ln2 -> ff1(+exact gelu) -> ff2(+residual)
//   heads: (W @ t4^T) with transposed epilogue writing (b,ci,code,p)
//
// Heavy GEMMs: f16 inputs, fp32 MFMA accum, 128x128 tile, 4 waves,
// BK=32, global_load_lds 16B staging (m97 structure).  ~172 MB workspace.
// ============================================================================

typedef _Float16 f16;
typedef _Float16 f16x2 __attribute__((ext_vector_type(2)));
typedef _Float16 f16x4 __attribute__((ext_vector_type(4)));
typedef _Float16 f16x8 __attribute__((ext_vector_type(8)));
typedef float f32x4 __attribute__((ext_vector_type(4)));

#define DEV __device__ __forceinline__

DEV void load_lds16(const f16* g, f16* l) {
  // dest must be wave-uniform base + lane*16B; our per-lane ptr equals exactly that.
  __builtin_amdgcn_global_load_lds((const __attribute__((address_space(1))) void*)(g),
                                   (__attribute__((address_space(3))) void*)(l), 16, 0, 0);
}

// ---------------------------------------------------------------------------
// FFT + reorder + feature pack.  One block per (b,c) image.
// ---------------------------------------------------------------------------
__global__ __launch_bounds__(256) void fft_feat_kernel(const float* __restrict__ x,
                                                       float* __restrict__ feat) {
  const int img = blockIdx.x;            // 0..31
  const int b = img >> 4, c = img & 15;
  __shared__ float xs[64 * 64];
  __shared__ float wre[64 * 33];
  __shared__ float wim[64 * 33];
  __shared__ float ct[64];
  __shared__ float st[64];
  const int tid = threadIdx.x;
  if (tid < 64) {
    float th = 0.09817477042468103f * (float)tid;  // 2*pi/64
    ct[tid] = cosf(th);
    st[tid] = sinf(th);
  }
  const float* xp = x + (size_t)img * 4096;
  for (int i = tid; i < 4096; i += 256) xs[i] = xp[i];
  __syncthreads();
  for (int i = tid; i < 64 * 33; i += 256) {
    int y = i / 33, kx = i - y * 33;
    float re = 0.f, im = 0.f;
    for (int xx = 0; xx < 64; ++xx) {
      float v = xs[y * 64 + xx];
      int idx = (kx * xx) & 63;
      re += v * ct[idx];
      im -= v * st[idx];
    }
    wre[i] = re;
    wim[i] = im;
  }
  __syncthreads();
  for (int i = tid; i < 64 * 33; i += 256) {
    int r = i / 33, kx = i - r * 33;
    int row;                       // source row in the SHIFTED array
    if (r == 0)      row = 32;
    else if (r == 63) row = 0;
    else if (r & 1)  row = 32 + (r + 1) / 2;
    else             row = 32 - r / 2;
    int ky = (row + 32) & 63;      // undo fftshift
    float re = 0.f, im = 0.f;
    for (int y = 0; y < 64; ++y) {
      int idx = (ky * y) & 63;
      float cr = ct[idx], sr = st[idx];
      float ar = wre[y * 33 + kx], ai = wim[y * 33 + kx];
      re += ar * cr + ai * sr;
      im += ai * cr - ar * sr;
    }
    re *= (1.0f / 64.0f);   // ortho norm 1/sqrt(4096)
    im *= (1.0f / 64.0f);
    float* fb = feat + ((size_t)b * 2112 + i) * 32;
    fb[c] = re;
    fb[16 + c] = im;
  }
}

// ---------------------------------------------------------------------------
__global__ __launch_bounds__(256) void init_shift_kernel(
    const float* __restrict__ feat, const float* __restrict__ iw,
    const float* __restrict__ ib, const float* __restrict__ cond,
    const float* __restrict__ dcw, const float* __restrict__ dcb,
    float* __restrict__ t) {
  const int idx = blockIdx.x * 256 + threadIdx.x;   // over 2*2112*1024
  if (idx >= 2 * 2112 * 1024) return;
  const int d = idx & 1023;
  const int bp = idx >> 10;
  const int b = bp / 2112, p = bp - b * 2112;
  float v;
  if (p == 0) {
    v = cond[b] * dcw[d] + dcb[d];
  } else {
    const float4* f4 = (const float4*)(feat + ((size_t)b * 2112 + (p - 1)) * 32);
    const float4* w4 = (const float4*)(iw + (size_t)d * 32);
    float acc = ib[d];
#pragma unroll
    for (int k = 0; k < 8; ++k) {
      const float4 a = f4[k], w = w4[k];
      acc += a.x * w.x + a.y * w.y + a.z * w.z + a.w * w.w;
    }
    v = acc;
  }
  t[idx] = v;
}

// ---------------------------------------------------------------------------
__global__ __launch_bounds__(256) void f32_to_f16_kernel(const float* __restrict__ in,
                                                         f16* __restrict__ out,
                                                         const int n4) {
  int i = blockIdx.x * 256 + threadIdx.x;
  const int stride = gridDim.x * 256;
  for (; i < n4; i += stride) {
    const float4 v = ((const float4*)in)[i];
    f16x4 o;
    o[0] = (f16)v.x; o[1] = (f16)v.y; o[2] = (f16)v.z; o[3] = (f16)v.w;
    ((f16x4*)out)[i] = o;
  }
}

// Fused 4-segment f32->f16 convert (one launch per layer's weights).
__global__ __launch_bounds__(256) void convert4_kernel(
    const float* __restrict__ s0, f16* __restrict__ d0, const int n0,
    const float* __restrict__ s1, f16* __restrict__ d1, const int n1,
    const float* __restrict__ s2, f16* __restrict__ d2, const int n2,
    const float* __restrict__ s3, f16* __restrict__ d3, const int n3) {
  int i = blockIdx.x * 256 + threadIdx.x;   // in float4 units
  const int total = n0 + n1 + n2 + n3;
  const int stride = gridDim.x * 256;
  for (; i < total; i += stride) {
    const float* s; f16* d; int j = i;
    if (j < n0)            { s = s0; d = d0; }
    else { j -= n0; if (j < n1) { s = s1; d = d1; }
    else { j -= n1; if (j < n2) { s = s2; d = d2; }
    else { j -= n2;          s = s3; d = d3; } } }
    const float4 v = ((const float4*)s)[j];
    f16x4 o;
    o[0] = (f16)v.x; o[1] = (f16)v.y; o[2] = (f16)v.z; o[3] = (f16)v.w;
    ((f16x4*)d)[j] = o;
  }
}

// ---------------------------------------------------------------------------
// LayerNorm (biased var, eps 1e-5), fp32 in -> f16 out. One block per row.
// ---------------------------------------------------------------------------
__global__ __launch_bounds__(256) void ln_kernel(const float* __restrict__ tin,
                                                 const float* __restrict__ g,
                                                 const float* __restrict__ bb,
                                                 f16* __restrict__ outp) {
  const int row = blockIdx.x;
  const int tid = threadIdx.x, lane = tid & 63, wid = tid >> 6;
  const float4 v = ((const float4*)(tin + (size_t)row * 1024))[tid];
  float s = v.x + v.y + v.z + v.w;
  float s2 = v.x * v.x + v.y * v.y + v.z * v.z + v.w * v.w;
#pragma unroll
  for (int o = 32; o; o >>= 1) {
    s += __shfl_down(s, o);
    s2 += __shfl_down(s2, o);
  }
  __shared__ float red[8];
  if (lane == 0) { red[wid] = s; red[4 + wid] = s2; }
  __syncthreads();
  const float mean = (red[0] + red[1] + red[2] + red[3]) * (1.f / 1024.f);
  const float var = (red[4] + red[5] + red[6] + red[7]) * (1.f / 1024.f) - mean * mean;
  const float rstd = rsqrtf(var + 1e-5f);
  const float4 gv = ((const float4*)g)[tid];
  const float4 bv = ((const float4*)bb)[tid];
  f16x4 o;
  o[0] = (f16)((v.x - mean) * rstd * gv.x + bv.x);
  o[1] = (f16)((v.y - mean) * rstd * gv.y + bv.y);
  o[2] = (f16)((v.z - mean) * rstd * gv.z + bv.z);
  o[3] = (f16)((v.w - mean) * rstd * gv.w + bv.w);
  ((f16x4*)(outp + (size_t)row * 1024))[tid] = o;
}

// ---------------------------------------------------------------------------
// RoPE (x + rope(x)) for q,k + head split to [bh][p][d]; V -> [bh][d][p] f16.
// ---------------------------------------------------------------------------
__global__ __launch_bounds__(256) void rope_split_kernel(const f16* __restrict__ qkv,
                                                         f16* __restrict__ qr,
                                                         f16* __restrict__ kr,
                                                         f16* __restrict__ vt) {
  const int z = blockIdx.y;   // b*8+h
  const int pt = blockIdx.x;  // 0..32
  const int b = z >> 3, h = z & 7;
  const int p0 = pt * 64;
  const int tid = threadIdx.x;
  __shared__ f16 vtile[64][130];

  for (int it = 0; it < 8; ++it) {
    int idx = it * 256 + tid;       // 64 rows x 32 dh-pairs
    int pr = idx >> 5, dp = idx & 31;
    int dh = dp * 2;
    int p = p0 + pr;
    const size_t base = ((size_t)(b * 2112 + p)) * 3072 + h * 128;
    float sn0, cs0, sn1, cs1;
    {
      float div0 = expf((float)dh * -0.14391156831212787f);        // -ln(1e4)/64
      float div1 = expf((float)(dh + 1) * -0.14391156831212787f);
      sincosf((float)p * div0, &sn0, &cs0);
      sincosf((float)p * div1, &sn1, &cs1);
    }
    {
      const f16x2 a = *(const f16x2*)(qkv + base + dh);
      const f16x2 c = *(const f16x2*)(qkv + base + 64 + dh);
      f16x2 lo, hi;
      lo[0] = (f16)((float)a[0] + (float)a[0] * cs0 - (float)c[0] * sn0);
      lo[1] = (f16)((float)a[1] + (float)a[1] * cs1 - (float)c[1] * sn1);
      hi[0] = (f16)((float)c[0] + (float)c[0] * cs0 + (float)a[0] * sn0);
      hi[1] = (f16)((float)c[1] + (float)c[1] * cs1 + (float)a[1] * sn1);
      f16* qo = qr + ((size_t)z * 2112 + p) * 128;
      *(f16x2*)(qo + dh) = lo;
      *(f16x2*)(qo + 64 + dh) = hi;
    }
    {
      const f16x2 a = *(const f16x2*)(qkv + base + 1024 + dh);
      const f16x2 c = *(const f16x2*)(qkv + base + 1024 + 64 + dh);
      f16x2 lo, hi;
      lo[0] = (f16)((float)a[0] + (float)a[0] * cs0 - (float)c[0] * sn0);
      lo[1] = (f16)((float)a[1] + (float)a[1] * cs1 - (float)c[1] * sn1);
      hi[0] = (f16)((float)c[0] + (float)c[0] * cs0 + (float)a[0] * sn0);
      hi[1] = (f16)((float)c[1] + (float)c[1] * cs1 + (float)a[1] * sn1);
      f16* ko = kr + ((size_t)z * 2112 + p) * 128;
      *(f16x2*)(ko + dh) = lo;
      *(f16x2*)(ko + 64 + dh) = hi;
    }
    {
      *(f16x2*)(&vtile[pr][dh]) = *(const f16x2*)(qkv + base + 2048 + dh);
      *(f16x2*)(&vtile[pr][64 + dh]) = *(const f16x2*)(qkv + base + 2048 + 64 + dh);
    }
  }
  __syncthreads();
  for (int it = 0; it < 16; ++it) {
    int idx = it * 256 + tid;       // 128 d x 32 pc-pairs
    int d = idx >> 5, pcp = idx & 31;
    int pc = pcp * 2;
    f16x2 o;
    o[0] = vtile[pc][d];
    o[1] = vtile[pc + 1][d];
    *(f16x2*)(vt + ((size_t)z * 128 + d) * 2112 + p0 + pc) = o;
  }
}

// ---------------------------------------------------------------------------
// Fused causal flash attention.  One block per (q-tile of 128 rows, z=b*8+h).
// 4 waves x 32 q-rows each (full 64-col kv-tile per wave -> row-local stats).
// Q in registers; K [64][128] and V^T [128][64] staged via global_load_lds
// with XOR-swizzled source (rule: linear dest + inv-swz src + swz read);
// P handed to PV via padded LDS [128][72].  Online softmax (m,l running).
// out: ao[(b*2112+m)*1024 + h*128 + d]  (f16)
// ---------------------------------------------------------------------------
__global__ __launch_bounds__(256) void attn_kernel(
    const f16* __restrict__ qr, const f16* __restrict__ kr,
    const f16* __restrict__ vt, f16* __restrict__ ao) {
  const int qt = (int)gridDim.x - 1 - (int)blockIdx.x;  // heavy tiles first
  const int z = blockIdx.y;
  const int b = z >> 3, h = z & 7;
  const int tid = threadIdx.x, wave = tid >> 6, lane = tid & 63;
  const int arow = lane & 15, lg = lane >> 4;
  const int mloc = wave * 32;

  __shared__ __align__(16) f16 Kl[64 * 128];   // [kv][d], xor-swizzled rows
  __shared__ __align__(16) f16 Vl[128 * 64];   // [d][kv], xor-swizzled rows
  __shared__ __align__(16) f16 Pl[128 * 72];   // [m][kv], padded

  const f16* krz = kr + (size_t)z * 270336;
  const f16* vtz = vt + (size_t)z * 270336;

  // Q fragments (A-operand): row=lane&15, k = ks*32 + lg*8 (+e)
  f16x8 qf[2][4];
#pragma unroll
  for (int i = 0; i < 2; ++i) {
    int qrow = qt * 128 + mloc + i * 16 + arow;
    qrow = qrow < 2112 ? qrow : 2111;
    const f16* qp = qr + ((size_t)z * 2112 + qrow) * 128 + lg * 8;
#pragma unroll
    for (int ks = 0; ks < 4; ++ks) qf[i][ks] = *(const f16x8*)(qp + ks * 32);
  }

  float mrow[2][4], lrow[2][4];
  f32x4 oacc[2][8];
#pragma unroll
  for (int i = 0; i < 2; ++i)
#pragma unroll
    for (int r = 0; r < 4; ++r) { mrow[i][r] = -1e30f; lrow[i][r] = 0.f; }
#pragma unroll
  for (int i = 0; i < 2; ++i)
#pragma unroll
    for (int j = 0; j < 8; ++j)
#pragma unroll
      for (int r = 0; r < 4; ++r) oacc[i][j][r] = 0.f;

  const int nt0 = 2 * (qt + 1);
  const int ntiles = nt0 < 33 ? nt0 : 33;   // kv tile 33 would be fully masked
  for (int kt = 0; kt < ntiles; ++kt) {
    // ---- stage K tile (rows kv 0..63, 256B rows, swizzled source)
#pragma unroll
    for (int s = 0; s < 4; ++s) {
      const int row = wave * 16 + s * 4 + lg;          // 0..63
      const int krow = kt * 64 + row;                  // <= 2111 always
      const int sb = (arow * 16) ^ ((row & 7) << 4);   // byte within row
      load_lds16(krz + (size_t)krow * 128 + (sb >> 1),
                 Kl + (wave * 16 + s * 4) * 128 + lane * 8);
    }
    __syncthreads();   // K ready (compiler drains vmcnt before s_barrier)

    // ---- issue V tile stage (rows d 0..127, 128B rows); drains at next barrier
#pragma unroll
    for (int s = 0; s < 4; ++s) {
      const int row = wave * 32 + s * 8 + (lane >> 3); // d row 0..127
      const int u = lane & 7;
      const int sb = (u * 16) ^ ((row & 7) << 4);      // byte within 128B row
      load_lds16(vtz + (size_t)row * 2112 + (size_t)kt * 64 + (sb >> 1),
                 Vl + (wave * 32 + s * 8) * 64 + lane * 8);
    }

    // ---- S = Q K^T for this wave's 32 rows x 64 cols
    f32x4 sa[2][4];
#pragma unroll
    for (int i = 0; i < 2; ++i)
#pragma unroll
      for (int j = 0; j < 4; ++j)
#pragma unroll
        for (int r = 0; r < 4; ++r) sa[i][j][r] = 0.f;
#pragma unroll
    for (int ks = 0; ks < 4; ++ks) {
      f16x8 bf[4];
#pragma unroll
      for (int j = 0; j < 4; ++j) {
        const int rowk = j * 16 + arow;
        bf[j] = *(const f16x8*)(Kl + rowk * 128 +
                                (((ks * 32 + lg * 8)) ^ ((rowk & 7) << 3)));
      }
#pragma unroll
      for (int i = 0; i < 2; ++i)
#pragma unroll
        for (int j = 0; j < 4; ++j)
          sa[i][j] = __builtin_amdgcn_mfma_f32_16x16x32_f16(qf[i][ks], bf[j], sa[i][j], 0, 0, 0);
    }

    // ---- scale + causal mask (only tiles straddling the diagonal)
    const bool dtile = (kt >= 2 * qt);
#pragma unroll
    for (int i = 0; i < 2; ++i)
#pragma unroll
      for (int j = 0; j < 4; ++j)
#pragma unroll
        for (int r = 0; r < 4; ++r) {
          float v = sa[i][j][r] * 0.08838834764831845f;
          if (dtile) {
            const int n = kt * 64 + j * 16 + arow;
            const int m = qt * 128 + mloc + i * 16 + lg * 4 + r;
            if (n > m) v = -1e30f;
          }
          sa[i][j][r] = v;
        }

    // ---- online softmax (rows = mloc + i*16 + lg*4 + r); write P to LDS
#pragma unroll
    for (int i = 0; i < 2; ++i) {
#pragma unroll
      for (int r = 0; r < 4; ++r) {
        float tmax = fmaxf(fmaxf(sa[i][0][r], sa[i][1][r]),
                           fmaxf(sa[i][2][r], sa[i][3][r]));
#pragma unroll
        for (int o = 8; o; o >>= 1) tmax = fmaxf(tmax, __shfl_xor(tmax, o));
        const float mnew = fmaxf(mrow[i][r], tmax);
        const float psc = __expf(mrow[i][r] - mnew);
        float ts = 0.f;
        const int prow = mloc + i * 16 + lg * 4 + r;
#pragma unroll
        for (int j = 0; j < 4; ++j) {
          const float p = __expf(sa[i][j][r] - mnew);
          ts += p;
          Pl[prow * 72 + j * 16 + arow] = (f16)p;
        }
#pragma unroll
        for (int o = 8; o; o >>= 1) ts += __shfl_xor(ts, o);
        lrow[i][r] = lrow[i][r] * psc + ts;
        mrow[i][r] = mnew;
#pragma unroll
        for (int j = 0; j < 8; ++j) oacc[i][j][r] *= psc;
      }
    }
    __syncthreads();   // V ready + (same-wave) P ordering

    // ---- O += P V   (A = P[m][kv] from Pl, B = V^T[d][kv] from Vl)
#pragma unroll
    for (int ks = 0; ks < 2; ++ks) {
      f16x8 pa[2];
#pragma unroll
      for (int i = 0; i < 2; ++i)
        pa[i] = *(const f16x8*)(Pl + (mloc + i * 16 + arow) * 72 + ks * 32 + lg * 8);
#pragma unroll
      for (int j = 0; j < 8; ++j) {
        const int rowv = j * 16 + arow;
        const f16x8 vb = *(const f16x8*)(Vl + rowv * 64 +
                                         (((ks * 32 + lg * 8)) ^ ((rowv & 7) << 3)));
#pragma unroll
        for (int i = 0; i < 2; ++i)
          oacc[i][j] = __builtin_amdgcn_mfma_f32_16x16x32_f16(pa[i], vb, oacc[i][j], 0, 0, 0);
      }
    }
    __syncthreads();   // all waves done with Kl/Vl before next tile's staging
  }

  // ---- epilogue: O / l -> ao
#pragma unroll
  for (int i = 0; i < 2; ++i)
#pragma unroll
    for (int r = 0; r < 4; ++r) {
      const int m = qt * 128 + mloc + i * 16 + lg * 4 + r;
      if (m < 2112) {
        const float inv = 1.f / lrow[i][r];
        f16* op = ao + ((size_t)(b * 2112 + m)) * 1024 + h * 128;
#pragma unroll
        for (int j = 0; j < 8; ++j) op[j * 16 + arow] = (f16)(oacc[i][j][r] * inv);
      }
    }
}

// ---------------------------------------------------------------------------
// Generic f16 MFMA GEMM: C[m][n] = sum_k A[m][k] * B[n][k]  (both row-major,
// K contiguous).  128x128 tile, 4 waves (2x2), BK=32, global_load_lds.
// MODE epilogues:
//   0: outF[m*ldc+n] = acc + bias[n]
//   1: outF[m*ldc+n] = acc + bias[n] + res[m*ldc+n]        (proj/ff2, res==outF ok)
//   2: outH[m*ldc+n] = gelu_exact(acc + bias[n])           (ff1)
//   3: head: outF[((b*16+ci)*1024+code)*2112+p] = acc+bias[m]
//   6: outH[m*ldc+n] = (f16)(acc + bias[n])                (qkv, f16 out)
// ---------------------------------------------------------------------------
template <int MODE>
__global__ __launch_bounds__(256) void gemm_f16(
    const f16* __restrict__ A, const f16* __restrict__ B,
    const int M, const int N, const int K, const int lda, const int ldb,
    const long sA, const long sB,
    const float* __restrict__ bias,
    float* outF, f16* outH, const float* res, const int ldc) {
  const int tn = blockIdx.x, tm = blockIdx.y, z = blockIdx.z;
  const int m0 = tm * 128, n0 = tn * 128;
  const f16* Ab = A + (size_t)z * sA;
  const f16* Bb = B + (size_t)z * sB;
  __shared__ __align__(16) f16 Ash[4096];
  __shared__ __align__(16) f16 Bsh[4096];
  const int tid = threadIdx.x;
  const int wave = tid >> 6, lane = tid & 63;
  const int wr = wave >> 1, wc = wave & 1;

  f32x4 acc[4][4];
#pragma unroll
  for (int i = 0; i < 4; ++i)
#pragma unroll
    for (int j = 0; j < 4; ++j)
#pragma unroll
      for (int r = 0; r < 4; ++r) acc[i][j][r] = 0.f;

  const int srow = wave * 16 + (lane >> 2);  // staged row (+ s*64)
  const int scol = (lane & 3) * 8;           // staged k-col
  const int ldsoff = wave * 512 + lane * 8;  // f16 elems (+ s*2048)
  const int arow = lane & 15, kg = lane >> 4;

  for (int k0 = 0; k0 < K; k0 += 32) {
#pragma unroll
    for (int s = 0; s < 2; ++s) {
      int ar = m0 + srow + s * 64; ar = ar < M ? ar : M - 1;
      load_lds16(Ab + (size_t)ar * lda + k0 + scol, Ash + s * 2048 + ldsoff);
      int br = n0 + srow + s * 64; br = br < N ? br : N - 1;
      load_lds16(Bb + (size_t)br * ldb + k0 + scol, Bsh + s * 2048 + ldsoff);
    }
    __syncthreads();
    f16x8 af[4], bf[4];
#pragma unroll
    for (int i = 0; i < 4; ++i)
      af[i] = *(const f16x8*)(Ash + (wr * 64 + i * 16 + arow) * 32 + kg * 8);
#pragma unroll
    for (int j = 0; j < 4; ++j)
      bf[j] = *(const f16x8*)(Bsh + (wc * 64 + j * 16 + arow) * 32 + kg * 8);
#pragma unroll
    for (int i = 0; i < 4; ++i)
#pragma unroll
      for (int j = 0; j < 4; ++j)
        acc[i][j] = __builtin_amdgcn_mfma_f32_16x16x32_f16(af[i], bf[j], acc[i][j], 0, 0, 0);
    __syncthreads();
  }

#pragma unroll
  for (int i = 0; i < 4; ++i) {
#pragma unroll
    for (int r = 0; r < 4; ++r) {
      const int m = m0 + wr * 64 + i * 16 + (lane >> 4) * 4 + r;
#pragma unroll
      for (int j = 0; j < 4; ++j) {
        const int n = n0 + wc * 64 + j * 16 + (lane & 15);
        float v = acc[i][j][r];
        if (MODE == 0) {
          if (m < M && n < N) outF[(size_t)m * ldc + n] = v + bias[n];
        } else if (MODE == 1) {
          if (m < M && n < N) {
            float t0 = res[(size_t)m * ldc + n];
            outF[(size_t)m * ldc + n] = v + bias[n] + t0;
          }
        } else if (MODE == 2) {
          if (m < M && n < N) {
            float g0 = v + bias[n];
            g0 = 0.5f * g0 * (1.f + erff(g0 * 0.70710678118654752f));
            outH[(size_t)m * ldc + n] = (f16)g0;
          }
        } else if (MODE == 3) {
          if (m < M && n < N) {
            int code = m >> 4, ci = m & 15;
            int bb2 = (n >= 2112) ? 1 : 0;
            int p = n - bb2 * 2112;
            outF[((size_t)(bb2 * 16 + ci) * 1024 + code) * 2112 + p] = v + bias[m];
          }
        } else {  // MODE 6
          if (m < M && n < N) outH[(size_t)m * ldc + n] = (f16)(v + bias[n]);
        }
      }
    }
  }
}

// ---------------------------------------------------------------------------
extern "C" void kernel_launch(void* const* d_in, const int* in_sizes, int n_in,
                              void* d_out, int out_size, void* d_ws, size_t ws_size,
                              hipStream_t stream) {
  const float* x      = (const float*)d_in[0];
  const float* cond   = (const float*)d_in[1];
  const float* init_w = (const float*)d_in[2];
  const float* init_b = (const float*)d_in[3];
  const float* dc_w   = (const float*)d_in[4];
  const float* dc_b   = (const float*)d_in[5];
  const float* ln1_g  = (const float*)d_in[6];
  const float* ln1_b  = (const float*)d_in[7];
  const float* qkv_w  = (const float*)d_in[8];
  const float* qkv_b  = (const float*)d_in[9];
  const float* proj_w = (const float*)d_in[10];
  const float* proj_b = (const float*)d_in[11];
  const float* ln2_g  = (const float*)d_in[12];
  const float* ln2_b  = (const float*)d_in[13];
  const float* ff1_w  = (const float*)d_in[14];
  const float* ff1_b  = (const float*)d_in[15];
  const float* ff2_w  = (const float*)d_in[16];
  const float* ff2_b  = (const float*)d_in[17];
  const float* mag_w  = (const float*)d_in[18];
  const float* mag_b  = (const float*)d_in[19];
  const float* phase_w = (const float*)d_in[20];
  const float* phase_b = (const float*)d_in[21];

  char* ws = (char*)d_ws;
  size_t off = 0;
  auto alloc = [&](size_t bytes) -> void* {
    void* p = ws + off;
    off += (bytes + 255) & ~(size_t)255;
    return p;
  };
  float* feat = (float*)alloc((size_t)2 * 2112 * 32 * 4);
  float* t    = (float*)alloc((size_t)4224 * 1024 * 4);
  f16* tln    = (f16*)alloc((size_t)4224 * 1024 * 2);
  f16* qkvh   = (f16*)alloc((size_t)4224 * 3072 * 2);
  f16* qr     = (f16*)alloc((size_t)16 * 2112 * 128 * 2);
  f16* kr     = (f16*)alloc((size_t)16 * 2112 * 128 * 2);
  f16* vt     = (f16*)alloc((size_t)16 * 2112 * 128 * 2);
  f16* ao     = (f16*)alloc((size_t)4224 * 1024 * 2);
  f16* ffh    = (f16*)alloc((size_t)4224 * 4096 * 2);
  f16* tf16   = (f16*)alloc((size_t)4224 * 1024 * 2);
  f16* wq     = (f16*)alloc((size_t)3145728 * 2);
  f16* wp     = (f16*)alloc((size_t)1048576 * 2);
  f16* w1     = (f16*)alloc((size_t)4194304 * 2);
  f16* w2     = (f16*)alloc((size_t)4194304 * 2);
  f16* wh     = (f16*)alloc((size_t)8388608 * 2);
  (void)ws_size; (void)n_in; (void)in_sizes; (void)out_size;

  fft_feat_kernel<<<32, 256, 0, stream>>>(x, feat);
  init_shift_kernel<<<16896, 256, 0, stream>>>(feat, init_w, init_b, cond, dc_w, dc_b, t);

  for (int l = 0; l < 8; ++l) {
    convert4_kernel<<<2048, 256, 0, stream>>>(
        qkv_w + (size_t)l * 3145728, wq, 3145728 / 4,
        proj_w + (size_t)l * 1048576, wp, 1048576 / 4,
        ff1_w + (size_t)l * 4194304, w1, 4194304 / 4,
        ff2_w + (size_t)l * 4194304, w2, 4194304 / 4);

    ln_kernel<<<4224, 256, 0, stream>>>(t, ln1_g + l * 1024, ln1_b + l * 1024, tln);
    gemm_f16<6><<<dim3(24, 33, 1), 256, 0, stream>>>(
        tln, wq, 4224, 3072, 1024, 1024, 1024, 0, 0,
        qkv_b + l * 3072, nullptr, qkvh, nullptr, 3072);
    rope_split_kernel<<<dim3(33, 16), 256, 0, stream>>>(qkvh, qr, kr, vt);
    attn_kernel<<<dim3(17, 16), 256, 0, stream>>>(qr, kr, vt, ao);
    gemm_f16<1><<<dim3(8, 33, 1), 256, 0, stream>>>(
        ao, wp, 4224, 1024, 1024, 1024, 1024, 0, 0,
        proj_b + l * 1024, t, nullptr, t, 1024);

    ln_kernel<<<4224, 256, 0, stream>>>(t, ln2_g + l * 1024, ln2_b + l * 1024, tln);
    gemm_f16<2><<<dim3(32, 33, 1), 256, 0, stream>>>(
        tln, w1, 4224, 4096, 1024, 1024, 1024, 0, 0,
        ff1_b + l * 4096, nullptr, ffh, nullptr, 4096);
    gemm_f16<1><<<dim3(8, 33, 1), 256, 0, stream>>>(
        ffh, w2, 4224, 1024, 4096, 4096, 4096, 0, 0,
        ff2_b + l * 1024, t, nullptr, t, 1024);
  }

  f32_to_f16_kernel<<<1024, 256, 0, stream>>>(t, tf16, (4224 * 1024) / 4);

  f32_to_f16_kernel<<<2048, 256, 0, stream>>>(mag_w, wh, 8388608 / 4);
  gemm_f16<3><<<dim3(33, 128, 1), 256, 0, stream>>>(
      wh, tf16, 16384, 4224, 512, 512, 1024, 0, 0,
      mag_b, (float*)d_out, nullptr, nullptr, 0);

  f32_to_f16_kernel<<<2048, 256, 0, stream>>>(phase_w, wh, 8388608 / 4);
  gemm_f16<3><<<dim3(33, 128, 1), 256, 0, stream>>>(
      wh, tf16 + 512, 16384, 4224, 512, 512, 1024, 0, 0,
      phase_b, (float*)d_out + 69206016, nullptr, nullptr, 0);
}